// Round 1
// baseline (174.020 us; speedup 1.0000x reference)
//
#include <hip/hip_runtime.h>

#define NN 8192
#define MM 8192
#define DD 256
#define NPART 4
#define MPART (MM / NPART)
#define BQ 64
#define BK 64

typedef short bf16x8 __attribute__((ext_vector_type(8)));
typedef short bf16x4 __attribute__((ext_vector_type(4)));
typedef float f32x4 __attribute__((ext_vector_type(4)));

static __device__ __forceinline__ short f2bf(float f) {
    unsigned u = __float_as_uint(f);
    u += 0x7fffu + ((u >> 16) & 1u);   // RNE
    return (short)(u >> 16);
}

// ---------------- projection: y = x @ W^T + b  -> bf16 ----------------
// grid: 1536 = 3 mats x 128 row-tiles x 4 col-tiles; 256 threads
__global__ __launch_bounds__(256, 2) void proj_kernel(
    const float* __restrict__ xq, const float* __restrict__ xkv,
    const float* __restrict__ Wq, const float* __restrict__ bq,
    const float* __restrict__ Wk, const float* __restrict__ bk,
    const float* __restrict__ Wv, const float* __restrict__ bv,
    short* __restrict__ qo, short* __restrict__ ko, short* __restrict__ vTo)
{
    __shared__ short Xs[64][264];
    __shared__ short Ws[64][264];

    const int bid = blockIdx.x;
    const int mat = bid >> 9;            // 0=q 1=k 2=v
    const int t = bid & 511;
    const int rt = t >> 2;               // row tile 0..127
    const int ct = t & 3;                // col tile 0..3
    const float* __restrict__ X = (mat == 0) ? xq : xkv;
    const float* __restrict__ W = (mat == 0) ? Wq : ((mat == 1) ? Wk : Wv);
    const float* __restrict__ bias = (mat == 0) ? bq : ((mat == 1) ? bk : bv);

    const int tid = threadIdx.x;
    const int lane = tid & 63;
    const int wv = tid >> 6;
    const int l15 = lane & 15;
    const int lg = lane >> 4;

    // stage X tile [64][256] and W tile [64][256] as bf16 (convert in-reg)
    #pragma unroll
    for (int i = 0; i < 16; ++i) {
        int c = i * 256 + tid;           // 0..4095 chunks of 4 floats
        int row = c >> 6;
        int col4 = (c & 63) << 2;
        f32x4 xv = *reinterpret_cast<const f32x4*>(X + (size_t)(rt * 64 + row) * DD + col4);
        f32x4 wr = *reinterpret_cast<const f32x4*>(W + (size_t)(ct * 64 + row) * DD + col4);
        bf16x4 xb, wb;
        #pragma unroll
        for (int j = 0; j < 4; ++j) { xb[j] = f2bf(xv[j]); wb[j] = f2bf(wr[j]); }
        *reinterpret_cast<bf16x4*>(&Xs[row][col4]) = xb;
        *reinterpret_cast<bf16x4*>(&Ws[row][col4]) = wb;
    }
    __syncthreads();

    f32x4 acc[4];
    #pragma unroll
    for (int f = 0; f < 4; ++f) acc[f] = f32x4{0.f, 0.f, 0.f, 0.f};

    #pragma unroll
    for (int kk = 0; kk < 8; ++kk) {
        bf16x8 a = *reinterpret_cast<const bf16x8*>(&Xs[wv * 16 + l15][kk * 32 + lg * 8]);
        #pragma unroll
        for (int f = 0; f < 4; ++f) {
            bf16x8 b = *reinterpret_cast<const bf16x8*>(&Ws[f * 16 + l15][kk * 32 + lg * 8]);
            acc[f] = __builtin_amdgcn_mfma_f32_16x16x32_bf16(a, b, acc[f], 0, 0, 0);
        }
    }

    #pragma unroll
    for (int f = 0; f < 4; ++f) {
        const int o = ct * 64 + f * 16 + l15;
        const float bsv = bias[o];
        if (mat == 2) {
            // store V transposed: vT[o][m], 4 consecutive m per lane
            bf16x4 pk;
            #pragma unroll
            for (int r = 0; r < 4; ++r) pk[r] = f2bf(acc[f][r] + bsv);
            const int mb = rt * 64 + wv * 16 + lg * 4;
            *reinterpret_cast<bf16x4*>(&vTo[(size_t)o * MM + mb]) = pk;
        } else {
            const float sc = (mat == 0) ? 0.0625f : 1.0f;   // fold 1/sqrt(D) into q
            short* __restrict__ dst = (mat == 0) ? qo : ko;
            #pragma unroll
            for (int r = 0; r < 4; ++r) {
                const int rowg = rt * 64 + wv * 16 + lg * 4 + r;
                dst[(size_t)rowg * DD + o] = f2bf((acc[f][r] + bsv) * sc);
            }
        }
    }
}

// ---------------- flash attention over one M-part ----------------
// grid: 512 = 128 q-tiles x 4 parts (XCD-clustered parts); 256 threads
__global__ __launch_bounds__(256, 2) void attn_kernel(
    const short* __restrict__ qg, const short* __restrict__ kg,
    const short* __restrict__ vT, float* __restrict__ outp,
    float* __restrict__ statm, float* __restrict__ statl)
{
    __shared__ short Ks[64][264];     // K tile  [m][d]
    __shared__ short Vs[256][72];     // vT tile [d][m]
    __shared__ short Ps[4][16][72];   // per-wave P tile [q][m]

    const int bid = blockIdx.x;
    const int x = bid & 7;            // XCD (round-robin dispatch assumption)
    const int p = x >> 1;             // part 0..3, 2 XCDs per part
    const int qt = ((bid >> 3) << 1) + (x & 1);  // 0..127
    const int q0 = qt * BQ;
    const int m0base = p * MPART;

    const int tid = threadIdx.x;
    const int lane = tid & 63;
    const int w = tid >> 6;
    const int l15 = lane & 15;
    const int lg = lane >> 4;

    // Q fragments hoisted to registers: wave w owns q rows q0+w*16 .. +15
    bf16x8 qf[8];
    const short* qrow = qg + (size_t)(q0 + w * 16 + l15) * DD;
    #pragma unroll
    for (int kk = 0; kk < 8; ++kk)
        qf[kk] = *reinterpret_cast<const bf16x8*>(qrow + kk * 32 + lg * 8);

    f32x4 oacc[16];
    #pragma unroll
    for (int f = 0; f < 16; ++f) oacc[f] = f32x4{0.f, 0.f, 0.f, 0.f};
    float mrun[4], lrun[4];
    #pragma unroll
    for (int r = 0; r < 4; ++r) { mrun[r] = -1e30f; lrun[r] = 0.f; }

    for (int it = 0; it < MPART / BK; ++it) {
        const int m0 = m0base + it * BK;
        __syncthreads();   // previous tile fully consumed
        // stage K tile [64][256]
        #pragma unroll
        for (int i = 0; i < 8; ++i) {
            int c = i * 256 + tid;
            int row = c >> 5;
            int col = (c & 31) << 3;
            bf16x8 v = *reinterpret_cast<const bf16x8*>(kg + (size_t)(m0 + row) * DD + col);
            *reinterpret_cast<bf16x8*>(&Ks[row][col]) = v;
        }
        // stage vT tile [256][64]
        #pragma unroll
        for (int i = 0; i < 8; ++i) {
            int c = i * 256 + tid;
            int row = c >> 3;
            int col = (c & 7) << 3;
            bf16x8 v = *reinterpret_cast<const bf16x8*>(vT + (size_t)row * MM + m0 + col);
            *reinterpret_cast<bf16x8*>(&Vs[row][col]) = v;
        }
        __syncthreads();

        // S = Q K^T (q pre-scaled by 1/16)
        f32x4 s[4];
        #pragma unroll
        for (int f = 0; f < 4; ++f) s[f] = f32x4{0.f, 0.f, 0.f, 0.f};
        #pragma unroll
        for (int kk = 0; kk < 8; ++kk) {
            #pragma unroll
            for (int f = 0; f < 4; ++f) {
                bf16x8 b = *reinterpret_cast<const bf16x8*>(&Ks[f * 16 + l15][kk * 32 + lg * 8]);
                s[f] = __builtin_amdgcn_mfma_f32_16x16x32_bf16(qf[kk], b, s[f], 0, 0, 0);
            }
        }

        // online softmax: lane's q rows are lg*4+r; reduce over m = {f}x{l15}
        float alpha[4];
        #pragma unroll
        for (int r = 0; r < 4; ++r) {
            float mx = fmaxf(fmaxf(s[0][r], s[1][r]), fmaxf(s[2][r], s[3][r]));
            mx = fmaxf(mx, __shfl_xor(mx, 1));
            mx = fmaxf(mx, __shfl_xor(mx, 2));
            mx = fmaxf(mx, __shfl_xor(mx, 4));
            mx = fmaxf(mx, __shfl_xor(mx, 8));
            const float mn = fmaxf(mrun[r], mx);
            alpha[r] = __expf(mrun[r] - mn);
            float rs = 0.f;
            #pragma unroll
            for (int f = 0; f < 4; ++f) {
                float pv = __expf(s[f][r] - mn);
                s[f][r] = pv;
                rs += pv;
            }
            rs += __shfl_xor(rs, 1);
            rs += __shfl_xor(rs, 2);
            rs += __shfl_xor(rs, 4);
            rs += __shfl_xor(rs, 8);
            lrun[r] = lrun[r] * alpha[r] + rs;
            mrun[r] = mn;
        }

        // P -> LDS (bf16), rescale accumulator
        #pragma unroll
        for (int f = 0; f < 4; ++f)
            #pragma unroll
            for (int r = 0; r < 4; ++r)
                Ps[w][lg * 4 + r][f * 16 + l15] = f2bf(s[f][r]);
        #pragma unroll
        for (int f = 0; f < 16; ++f)
            #pragma unroll
            for (int r = 0; r < 4; ++r)
                oacc[f][r] *= alpha[r];

        // PV: out[q][d] += P[q][m] * vT[d][m]
        #pragma unroll
        for (int ks = 0; ks < 2; ++ks) {
            bf16x8 pa = *reinterpret_cast<const bf16x8*>(&Ps[w][l15][ks * 32 + lg * 8]);
            #pragma unroll
            for (int f = 0; f < 16; ++f) {
                bf16x8 b = *reinterpret_cast<const bf16x8*>(&Vs[f * 16 + l15][ks * 32 + lg * 8]);
                oacc[f] = __builtin_amdgcn_mfma_f32_16x16x32_bf16(pa, b, oacc[f], 0, 0, 0);
            }
        }
    }

    // epilogue: unnormalized partial + stats
    const int qrow_g = q0 + w * 16 + lg * 4;
    float* ob = outp + ((size_t)p * NN + qrow_g) * DD;
    #pragma unroll
    for (int f = 0; f < 16; ++f) {
        const int d = f * 16 + l15;
        #pragma unroll
        for (int r = 0; r < 4; ++r)
            ob[(size_t)r * DD + d] = oacc[f][r];
    }
    if (l15 == 0) {
        #pragma unroll
        for (int r = 0; r < 4; ++r) {
            statm[(size_t)p * NN + qrow_g + r] = mrun[r];
            statl[(size_t)p * NN + qrow_g + r] = lrun[r];
        }
    }
}

// ---------------- combine partials ----------------
__global__ __launch_bounds__(256) void combine_kernel(
    const float* __restrict__ outp, const float* __restrict__ statm,
    const float* __restrict__ statl, float* __restrict__ out)
{
    const int q = blockIdx.x;
    const int d = threadIdx.x;
    float mv[NPART], lv[NPART];
    float mM = -1e30f;
    #pragma unroll
    for (int p = 0; p < NPART; ++p) {
        mv[p] = statm[(size_t)p * NN + q];
        lv[p] = statl[(size_t)p * NN + q];
        mM = fmaxf(mM, mv[p]);
    }
    float L = 0.f, acc = 0.f;
    #pragma unroll
    for (int p = 0; p < NPART; ++p) {
        const float wgt = __expf(mv[p] - mM);
        L += wgt * lv[p];
        acc += wgt * outp[((size_t)p * NN + q) * DD + d];
    }
    out[(size_t)q * DD + d] = acc / L;
}

extern "C" void kernel_launch(void* const* d_in, const int* in_sizes, int n_in,
                              void* d_out, int out_size, void* d_ws, size_t ws_size,
                              hipStream_t stream) {
    const float* xq  = (const float*)d_in[0];
    const float* xkv = (const float*)d_in[1];
    const float* Wq  = (const float*)d_in[2];
    const float* bq  = (const float*)d_in[3];
    const float* Wk  = (const float*)d_in[4];
    const float* bk  = (const float*)d_in[5];
    const float* Wv  = (const float*)d_in[6];
    const float* bv  = (const float*)d_in[7];
    float* out = (float*)d_out;

    char* ws = (char*)d_ws;
    short* qb  = (short*)(ws);                       // 4 MiB  bf16 q (pre-scaled)
    short* kb  = (short*)(ws + ((size_t)4 << 20));   // 4 MiB  bf16 k
    short* vTb = (short*)(ws + ((size_t)8 << 20));   // 4 MiB  bf16 v^T [D][M]
    float* outp = (float*)(ws + ((size_t)12 << 20)); // 32 MiB partials [NPART][N][D]
    float* sm = (float*)(ws + ((size_t)12 << 20) + (size_t)NPART * NN * DD * 4);
    float* sl = sm + (size_t)NPART * NN;

    proj_kernel<<<1536, 256, 0, stream>>>(xq, xkv, Wq, bq, Wk, bk, Wv, bv, qb, kb, vTb);
    attn_kernel<<<512, 256, 0, stream>>>(qb, kb, vTb, outp, sm, sl);
    combine_kernel<<<8192, 256, 0, stream>>>(outp, sm, sl, out);
}

// Round 2
// 167.170 us; speedup vs baseline: 1.0410x; 1.0410x over previous
//
#include <hip/hip_runtime.h>

#define NN 8192
#define MM 8192
#define DD 256
#define NPART 4
#define MPART (MM / NPART)   // 2048
#define BK 32
#define NT (MPART / BK)      // 64

typedef short bf16x8 __attribute__((ext_vector_type(8)));
typedef short bf16x4 __attribute__((ext_vector_type(4)));
typedef float f32x4 __attribute__((ext_vector_type(4)));

// async global->LDS, 16B per lane; LDS dest = wave-uniform base + lane*16
#define GLL16(src, dst) __builtin_amdgcn_global_load_lds( \
    (__attribute__((address_space(1))) void*)(src), \
    (__attribute__((address_space(3))) void*)(dst), 16, 0, 0)

static __device__ __forceinline__ short f2bf(float f) {
    unsigned u = __float_as_uint(f);
    u += 0x7fffu + ((u >> 16) & 1u);   // RNE
    return (short)(u >> 16);
}

// ---------------- projection: y = x @ W^T + b  -> bf16 ----------------
// grid: 1536 = 3 mats x 128 row-tiles x 4 col-tiles; 256 threads
__global__ __launch_bounds__(256, 2) void proj_kernel(
    const float* __restrict__ xq, const float* __restrict__ xkv,
    const float* __restrict__ Wq, const float* __restrict__ bq,
    const float* __restrict__ Wk, const float* __restrict__ bk,
    const float* __restrict__ Wv, const float* __restrict__ bv,
    short* __restrict__ qo, short* __restrict__ ko, short* __restrict__ vTo)
{
    __shared__ short Xs[64][264];
    __shared__ short Ws[64][264];

    const int bid = blockIdx.x;
    const int mat = bid >> 9;            // 0=q 1=k 2=v
    const int t = bid & 511;
    const int rt = t >> 2;               // row tile 0..127
    const int ct = t & 3;                // col tile 0..3
    const float* __restrict__ X = (mat == 0) ? xq : xkv;
    const float* __restrict__ W = (mat == 0) ? Wq : ((mat == 1) ? Wk : Wv);
    const float* __restrict__ bias = (mat == 0) ? bq : ((mat == 1) ? bk : bv);

    const int tid = threadIdx.x;
    const int lane = tid & 63;
    const int wv = tid >> 6;
    const int l15 = lane & 15;
    const int lg = lane >> 4;

    #pragma unroll
    for (int i = 0; i < 16; ++i) {
        int c = i * 256 + tid;
        int row = c >> 6;
        int col4 = (c & 63) << 2;
        f32x4 xv = *reinterpret_cast<const f32x4*>(X + (size_t)(rt * 64 + row) * DD + col4);
        f32x4 wr = *reinterpret_cast<const f32x4*>(W + (size_t)(ct * 64 + row) * DD + col4);
        bf16x4 xb, wb;
        #pragma unroll
        for (int j = 0; j < 4; ++j) { xb[j] = f2bf(xv[j]); wb[j] = f2bf(wr[j]); }
        *reinterpret_cast<bf16x4*>(&Xs[row][col4]) = xb;
        *reinterpret_cast<bf16x4*>(&Ws[row][col4]) = wb;
    }
    __syncthreads();

    f32x4 acc[4];
    #pragma unroll
    for (int f = 0; f < 4; ++f) acc[f] = f32x4{0.f, 0.f, 0.f, 0.f};

    #pragma unroll
    for (int kk = 0; kk < 8; ++kk) {
        bf16x8 a = *reinterpret_cast<const bf16x8*>(&Xs[wv * 16 + l15][kk * 32 + lg * 8]);
        #pragma unroll
        for (int f = 0; f < 4; ++f) {
            bf16x8 b = *reinterpret_cast<const bf16x8*>(&Ws[f * 16 + l15][kk * 32 + lg * 8]);
            acc[f] = __builtin_amdgcn_mfma_f32_16x16x32_bf16(a, b, acc[f], 0, 0, 0);
        }
    }

    #pragma unroll
    for (int f = 0; f < 4; ++f) {
        const int o = ct * 64 + f * 16 + l15;
        const float bsv = bias[o];
        if (mat == 2) {
            bf16x4 pk;
            #pragma unroll
            for (int r = 0; r < 4; ++r) pk[r] = f2bf(acc[f][r] + bsv);
            const int mb = rt * 64 + wv * 16 + lg * 4;
            *reinterpret_cast<bf16x4*>(&vTo[(size_t)o * MM + mb]) = pk;
        } else {
            // q: fold 1/sqrt(D)=1/16 AND log2(e) (softmax done in exp2 domain)
            const float sc = (mat == 0) ? 0.0625f * 1.44269504089f : 1.0f;
            short* __restrict__ dst = (mat == 0) ? qo : ko;
            #pragma unroll
            for (int r = 0; r < 4; ++r) {
                const int rowg = rt * 64 + wv * 16 + lg * 4 + r;
                dst[(size_t)rowg * DD + o] = f2bf((acc[f][r] + bsv) * sc);
            }
        }
    }
}

// ---------------- flash attention over one M-part ----------------
// grid: 512 = 128 q-tiles x 4 parts (XCD-pinned parts); 256 threads
// Double-buffered K/V staged by global_load_lds; K source pre-swizzled so
// swizzled ds_read_b128 is bank-conflict-free; V [d][m] layout naturally so.
__global__ __launch_bounds__(256, 2) void attn_kernel(
    const short* __restrict__ qg, const short* __restrict__ kg,
    const short* __restrict__ vT, float* __restrict__ outp,
    float* __restrict__ statm, float* __restrict__ statl)
{
    __shared__ short Ks[2][BK * DD];      // 2 x 16KB, rows 512B, phys chunk c holds logical c^(r&7)
    __shared__ short Vs[2][DD * BK];      // 2 x 16KB, [d][m] rows 64B, linear
    __shared__ short Ps[4][16][40];       // per-wave P tile

    const int bid = blockIdx.x;
    const int x = bid & 7;                // XCD (round-robin dispatch)
    const int p = x >> 1;                 // part: 2 XCDs per part -> K/V slice L2-resident
    const int qt = ((bid >> 3) << 1) + (x & 1);
    const int q0 = qt * 64;
    const int m0base = p * MPART;

    const int tid = threadIdx.x;
    const int lane = tid & 63;
    const int w = tid >> 6;
    const int l15 = lane & 15;
    const int lg = lane >> 4;

    // Q fragments in registers (wave w owns q rows q0+w*16..+15)
    bf16x8 qf[8];
    const short* qrow = qg + (size_t)(q0 + w * 16 + l15) * DD;
    #pragma unroll
    for (int kk = 0; kk < 8; ++kk)
        qf[kk] = *reinterpret_cast<const bf16x8*>(qrow + kk * 32 + lg * 8);

    // staging geometry (each wave: 4 K-instrs + 4 V-instrs of 1KB)
    // K instr j: phys rows 2j,2j+1; lane: r=2j+(lane>>5), chunk=lane&31, src chunk=(lane&31)^(r&7)
    // V instr j: d rows j*16..+15; lane: d=j*16+(lane>>2), m-chunk=lane&3
    int krow_i[4], kcol_i[4], vrow_i[4], ldsK_i[4], ldsV_i[4];
    #pragma unroll
    for (int i = 0; i < 4; ++i) {
        const int j = w * 4 + i;
        const int r = 2 * j + (lane >> 5);
        krow_i[i] = r;
        kcol_i[i] = ((lane & 31) ^ (r & 7)) * 8;            // shorts
        vrow_i[i] = j * 16 + (lane >> 2);
        ldsK_i[i] = __builtin_amdgcn_readfirstlane(j * 512); // shorts
        ldsV_i[i] = __builtin_amdgcn_readfirstlane(j * 512);
    }
    const int vcol = (lane & 3) * 8;                         // shorts

    f32x4 oacc[16];
    #pragma unroll
    for (int f = 0; f < 16; ++f) oacc[f] = f32x4{0.f, 0.f, 0.f, 0.f};
    f32x4 lacc = f32x4{0.f, 0.f, 0.f, 0.f};
    float mrun[4];
    #pragma unroll
    for (int r = 0; r < 4; ++r) mrun[r] = -1e30f;

    // ones-column B-frag for row-sum-via-MFMA (col n==0 only)
    bf16x8 onesf;
    {
        const short ov = (l15 == 0) ? (short)0x3F80 : (short)0;
        #pragma unroll
        for (int j = 0; j < 8; ++j) onesf[j] = ov;
    }
    const int swz = (l15 & 7) << 4;   // byte xor for K reads

    // prologue: stage tile 0 into buf 0
    {
        const int m0 = m0base;
        #pragma unroll
        for (int i = 0; i < 4; ++i) {
            GLL16(kg + (size_t)(m0 + krow_i[i]) * DD + kcol_i[i], &Ks[0][ldsK_i[i]]);
            GLL16(vT + (size_t)vrow_i[i] * MM + m0 + vcol, &Vs[0][ldsV_i[i]]);
        }
    }
    __syncthreads();

    int cur = 0;
    #pragma unroll 1
    for (int t = 0; t < NT; ++t) {
        // issue next-tile stage first (latency hidden under compute)
        if (t + 1 < NT) {
            const int m0 = m0base + (t + 1) * BK;
            #pragma unroll
            for (int i = 0; i < 4; ++i) {
                GLL16(kg + (size_t)(m0 + krow_i[i]) * DD + kcol_i[i], &Ks[cur ^ 1][ldsK_i[i]]);
                GLL16(vT + (size_t)vrow_i[i] * MM + m0 + vcol, &Vs[cur ^ 1][ldsV_i[i]]);
            }
        }

        // S = Q K^T (exp2-domain logits; swizzled reads)
        f32x4 s[2];
        s[0] = f32x4{0.f, 0.f, 0.f, 0.f};
        s[1] = f32x4{0.f, 0.f, 0.f, 0.f};
        const char* kbase = (const char*)&Ks[cur][0];
        __builtin_amdgcn_s_setprio(1);
        #pragma unroll
        for (int kk = 0; kk < 8; ++kk) {
            #pragma unroll
            for (int f = 0; f < 2; ++f) {
                const int row = f * 16 + l15;
                bf16x8 b = *reinterpret_cast<const bf16x8*>(
                    kbase + row * 512 + ((kk * 64 + lg * 16) ^ swz));
                s[f] = __builtin_amdgcn_mfma_f32_16x16x32_bf16(qf[kk], b, s[f], 0, 0, 0);
            }
        }
        __builtin_amdgcn_s_setprio(0);

        // online softmax (defer-max, THR=11.5 in log2 domain)
        float nmx[4];
        bool need = false;
        #pragma unroll
        for (int r = 0; r < 4; ++r) {
            float mx = fmaxf(s[0][r], s[1][r]);
            mx = fmaxf(mx, __shfl_xor(mx, 1));
            mx = fmaxf(mx, __shfl_xor(mx, 2));
            mx = fmaxf(mx, __shfl_xor(mx, 4));
            mx = fmaxf(mx, __shfl_xor(mx, 8));
            nmx[r] = mx;
            need = need || (mx > mrun[r] + 11.5f);
        }
        if (__any(need)) {
            #pragma unroll
            for (int r = 0; r < 4; ++r) {
                const float mn = fmaxf(mrun[r], nmx[r]);
                const float a = __builtin_amdgcn_exp2f(mrun[r] - mn);
                mrun[r] = mn;
                lacc[r] *= a;
                #pragma unroll
                for (int f = 0; f < 16; ++f) oacc[f][r] *= a;
            }
        }

        // P = exp2(s - m) -> LDS (per-wave tile, no barrier needed)
        #pragma unroll
        for (int f = 0; f < 2; ++f)
            #pragma unroll
            for (int r = 0; r < 4; ++r)
                Ps[w][lg * 4 + r][f * 16 + l15] = f2bf(__builtin_amdgcn_exp2f(s[f][r] - mrun[r]));

        bf16x8 pa = *reinterpret_cast<const bf16x8*>(&Ps[w][l15][lg * 8]);

        // PV + row-sum (ones column) accumulate
        __builtin_amdgcn_s_setprio(1);
        lacc = __builtin_amdgcn_mfma_f32_16x16x32_bf16(pa, onesf, lacc, 0, 0, 0);
        #pragma unroll
        for (int f = 0; f < 16; ++f) {
            bf16x8 b = *reinterpret_cast<const bf16x8*>(&Vs[cur][(f * 16 + l15) * 32 + lg * 8]);
            oacc[f] = __builtin_amdgcn_mfma_f32_16x16x32_bf16(pa, b, oacc[f], 0, 0, 0);
        }
        __builtin_amdgcn_s_setprio(0);

        // drain stage(t+1) + all waves done reading buf[cur] (single barrier/tile)
        __syncthreads();
        cur ^= 1;
    }

    // epilogue: unnormalized partial + stats (log2-domain m)
    const int qrow_g = q0 + w * 16 + lg * 4;
    float* ob = outp + ((size_t)p * NN + qrow_g) * DD;
    #pragma unroll
    for (int f = 0; f < 16; ++f) {
        const int d = f * 16 + l15;
        #pragma unroll
        for (int r = 0; r < 4; ++r)
            ob[(size_t)r * DD + d] = oacc[f][r];
    }
    if (l15 == 0) {
        #pragma unroll
        for (int r = 0; r < 4; ++r) {
            statm[(size_t)p * NN + qrow_g + r] = mrun[r];
            statl[(size_t)p * NN + qrow_g + r] = lacc[r];
        }
    }
}

// ---------------- combine partials (exp2 domain) ----------------
__global__ __launch_bounds__(256) void combine_kernel(
    const float* __restrict__ outp, const float* __restrict__ statm,
    const float* __restrict__ statl, float* __restrict__ out)
{
    const int q = blockIdx.x;
    const int d = threadIdx.x;
    float mv[NPART], lv[NPART];
    float mM = -1e30f;
    #pragma unroll
    for (int p = 0; p < NPART; ++p) {
        mv[p] = statm[(size_t)p * NN + q];
        lv[p] = statl[(size_t)p * NN + q];
        mM = fmaxf(mM, mv[p]);
    }
    float L = 0.f, acc = 0.f;
    #pragma unroll
    for (int p = 0; p < NPART; ++p) {
        const float wgt = exp2f(mv[p] - mM);
        L += wgt * lv[p];
        acc += wgt * outp[((size_t)p * NN + q) * DD + d];
    }
    out[(size_t)q * DD + d] = acc / L;
}

extern "C" void kernel_launch(void* const* d_in, const int* in_sizes, int n_in,
                              void* d_out, int out_size, void* d_ws, size_t ws_size,
                              hipStream_t stream) {
    const float* xq  = (const float*)d_in[0];
    const float* xkv = (const float*)d_in[1];
    const float* Wq  = (const float*)d_in[2];
    const float* bq  = (const float*)d_in[3];
    const float* Wk  = (const float*)d_in[4];
    const float* bk  = (const float*)d_in[5];
    const float* Wv  = (const float*)d_in[6];
    const float* bv  = (const float*)d_in[7];
    float* out = (float*)d_out;

    char* ws = (char*)d_ws;
    short* qb  = (short*)(ws);                       // 4 MiB  bf16 q (pre-scaled)
    short* kb  = (short*)(ws + ((size_t)4 << 20));   // 4 MiB  bf16 k
    short* vTb = (short*)(ws + ((size_t)8 << 20));   // 4 MiB  bf16 v^T [D][M]
    float* outp = (float*)(ws + ((size_t)12 << 20)); // 32 MiB partials [NPART][N][D]
    float* sm = (float*)(ws + ((size_t)12 << 20) + (size_t)NPART * NN * DD * 4);
    float* sl = sm + (size_t)NPART * NN;

    proj_kernel<<<1536, 256, 0, stream>>>(xq, xkv, Wq, bq, Wk, bk, Wv, bv, qb, kb, vTb);
    attn_kernel<<<512, 256, 0, stream>>>(qb, kb, vTb, outp, sm, sl);
    combine_kernel<<<8192, 256, 0, stream>>>(outp, sm, sl, out);
}